// Round 7
// baseline (203.118 us; speedup 1.0000x reference)
//
#include <hip/hip_runtime.h>
#include <hip/hip_bf16.h>
#include <math.h>

#define B_    4
#define N_    1024
#define L_    77

typedef float f4 __attribute__((ext_vector_type(4)));
typedef short bf8 __attribute__((ext_vector_type(8)));
typedef short s4v __attribute__((ext_vector_type(4)));

#if __has_builtin(__builtin_amdgcn_exp2f)
#define EXP2(x) __builtin_amdgcn_exp2f(x)
#else
#define EXP2(x) exp2f(x)
#endif

// async global->LDS, 16B per lane; lds dest = wave-uniform base + lane*16
typedef const __attribute__((address_space(1))) void* gas_t;
typedef __attribute__((address_space(3))) void* las_t;
#define GLL16(g, l) __builtin_amdgcn_global_load_lds((gas_t)(const void*)(g), (las_t)(void*)(l), 16, 0, 0)

__device__ __forceinline__ float fs(short s) {
    unsigned u = ((unsigned)(unsigned short)s) << 16;
    return __builtin_bit_cast(float, u);
}
__device__ __forceinline__ short sf(float f) {
    unsigned u = __builtin_bit_cast(unsigned, f);
    unsigned r = (u + 0x7FFF + ((u >> 16) & 1)) >> 16;
    return (short)r;
}
__device__ __forceinline__ bf8 zero8() { bf8 v; for (int i = 0; i < 8; ++i) v[i] = 0; return v; }
__device__ __forceinline__ f4 zerof4() { f4 v; for (int i = 0; i < 4; ++i) v[i] = 0.f; return v; }

#define MFMA(a, b, c) __builtin_amdgcn_mfma_f32_16x16x32_bf16((a), (b), (c), 0, 0, 0)

// ---------------------------------------------------------------------------
// Full GroupNorm body (gn1 inside prep_mega).
// src fp32 [b][512][1024] ([c][n]) -> dst bf16 [b][1024][512] ([n][c]).
// ---------------------------------------------------------------------------
__device__ __forceinline__ void gn_body(const float* __restrict__ src,
                                        const float* __restrict__ w,
                                        const float* __restrict__ bs,
                                        short* __restrict__ dst, int g, int b)
{
    const float* xb = src + ((size_t)b * 512 + g * 16) * 1024;
    float s = 0.f, ss = 0.f;
    for (int l = threadIdx.x; l < 4096; l += 256) {
        float4 v = *(const float4*)(xb + l * 4);
        s += v.x + v.y + v.z + v.w;
        ss += v.x * v.x + v.y * v.y + v.z * v.z + v.w * v.w;
    }
    for (int off = 32; off; off >>= 1) {
        s  += __shfl_down(s,  off);
        ss += __shfl_down(ss, off);
    }
    __shared__ float sred[8], ssred[8];
    int wid = threadIdx.x >> 6;
    if ((threadIdx.x & 63) == 0) { sred[wid] = s; ssred[wid] = ss; }
    __syncthreads();
    if (threadIdx.x == 0) {
        float S = 0.f, SS = 0.f;
        for (int i = 0; i < 4; ++i) { S += sred[i]; SS += ssred[i]; }
        float mu = S * (1.f / 16384.f);
        float var = SS * (1.f / 16384.f) - mu * mu;
        sred[4] = mu; ssred[4] = rsqrtf(var + 1e-5f);
    }
    __syncthreads();
    float mu = sred[4], rs = ssred[4];

    int c4 = threadIdx.x & 3, nb = threadIdx.x >> 2;
    int c = g * 16 + c4 * 4;
    float4 wv = *(const float4*)(w + c);
    float4 bv = *(const float4*)(bs + c);
    for (int rep = 0; rep < 16; ++rep) {
        int n = rep * 64 + nb;
        float v0 = xb[(size_t)(c4 * 4 + 0) * 1024 + n];
        float v1 = xb[(size_t)(c4 * 4 + 1) * 1024 + n];
        float v2 = xb[(size_t)(c4 * 4 + 2) * 1024 + n];
        float v3 = xb[(size_t)(c4 * 4 + 3) * 1024 + n];
        s4v hb;
        hb[0] = sf((v0 - mu) * rs * wv.x + bv.x);
        hb[1] = sf((v1 - mu) * rs * wv.y + bv.y);
        hb[2] = sf((v2 - mu) * rs * wv.z + bv.z);
        hb[3] = sf((v3 - mu) * rs * wv.w + bv.w);
        *(s4v*)(dst + ((size_t)b * 1024 + n) * 512 + c) = hb;
    }
}

// ---------------------------------------------------------------------------
// prep mega-kernel: gn1 + tab (log2e-scaled) + gstat zero + 6 weight
// transposes + ctx->bf16.
// ---------------------------------------------------------------------------
__device__ __forceinline__ void wtile(const float* __restrict__ in, short* __restrict__ out,
                                      int K, int J, int tile, int tid, float (*t)[33])
{
    int jt = J >> 5;
    int j0 = (tile % jt) * 32, k0 = (tile / jt) * 32;
    int tx = tid & 31, ty = tid >> 5;
#pragma unroll
    for (int i = 0; i < 4; ++i)
        t[ty + i * 8][tx] = in[(size_t)(k0 + ty + i * 8) * J + j0 + tx];
    __syncthreads();
#pragma unroll
    for (int i = 0; i < 4; ++i)
        out[(size_t)(j0 + ty + i * 8) * K + k0 + tx] = sf(t[tx][ty + i * 8]);
}

__global__ __launch_bounds__(256)
void prep_mega(const float* __restrict__ x, const float* __restrict__ gn1w,
               const float* __restrict__ gn1b, short* __restrict__ h1b,
               const float* __restrict__ wl, short* __restrict__ tab,
               float* __restrict__ gstat,
               const float* __restrict__ qkvw, short* __restrict__ qkvwT,
               const float* __restrict__ faow, short* __restrict__ faowT,
               const float* __restrict__ caqw, short* __restrict__ caqwT,
               const float* __restrict__ cakw, short* __restrict__ cakwT,
               const float* __restrict__ cavw, short* __restrict__ cavwT,
               const float* __restrict__ caow, short* __restrict__ caowT,
               const float* __restrict__ ctx, short* __restrict__ ctxb)
{
    __shared__ float tls[32][33];
    int bid = blockIdx.x, tid = threadIdx.x;
    if (bid < 128) { gn_body(x, gn1w, gn1b, h1b, bid & 31, bid >> 5); return; }
    bid -= 128;
    if (bid < 16) {
        if (bid == 0) gstat[tid] = 0.f;       // 256 floats = 4 b x 32 g x 2
        int idx = bid * 256 + tid;
        if (idx < 3969) {
            int i = idx / 63, j = idx - i * 63;
            float dy = (float)(i - 31), dx = (float)(j - 31);
            float dist = sqrtf(dy * dy + dx * dx + 1e-8f);
            float den = fabsf(wl[0]) * 32.0f + 1e-6f;
            tab[idx] = sf(0.1f * cosf(6.283185307179586f * dist / den) * 1.4426950408889634f);
        }
        return;
    }
    bid -= 16;
    if (bid < 768) { wtile(qkvw, qkvwT, 512, 1536, bid, tid, tls); return; }
    bid -= 768;
    if (bid < 256) { wtile(faow, faowT, 512, 512, bid, tid, tls); return; }
    bid -= 256;
    if (bid < 256) { wtile(caqw, caqwT, 512, 512, bid, tid, tls); return; }
    bid -= 256;
    if (bid < 384) { wtile(cakw, cakwT, 768, 512, bid, tid, tls); return; }
    bid -= 384;
    if (bid < 384) { wtile(cavw, cavwT, 768, 512, bid, tid, tls); return; }
    bid -= 384;
    if (bid < 256) { wtile(caow, caowT, 512, 512, bid, tid, tls); return; }
    bid -= 256;
    int base = bid * 1024 + tid * 4;
    float4 v = *(const float4*)(ctx + base);
    s4v o; o[0] = sf(v.x); o[1] = sf(v.y); o[2] = sf(v.z); o[3] = sf(v.w);
    *(s4v*)(ctxb + base) = o;
}

// ---------------------------------------------------------------------------
// MFMA GEMM body, 64x128 tile, 4 waves (2x2 of 32x64), dbuf LDS via
// global_load_lds (linear As [64][32], Ws [128][32] shorts), one barrier per
// K-step; next-step loads issued BEFORE the MFMAs (m97 schedule).
// out[b][m][j] = sum_k A[b][m][k] * Wt[b][j][k]
// EPI 1: fp32 store + bias[m] + res   EPI 2: EPI1 + group-stat atomics
// EPI 3: qkv (q|k store / V transpose)  EPI 4: kv (k store / v2t transpose)
// NOTE: no m<M staging guard (global_load_lds can't predicate) — OOB rows
// read inside d_ws (finite) and never reach guarded stores / P=0 keys.
// ---------------------------------------------------------------------------
template<int EPI>
__device__ __forceinline__ void gemm_body(
    short* As, short* Ws, int j0, int m0, int b,
    const short* __restrict__ A, const short* __restrict__ Wt,
    const float* __restrict__ bias, const float* __restrict__ res,
    void* __restrict__ outv, void* __restrict__ out2v, float* __restrict__ gstat,
    int M, int K, int J, long aStride, long wStride, long oStride, long o2Stride)
{
    int tid = threadIdx.x, w = tid >> 6, lane = tid & 63;
    int lr = lane & 15, lg = lane >> 4;
    int wr = w >> 1, wc = w & 1;
    const short* Ab  = A  + (size_t)b * aStride;
    const short* Wtb = Wt + (size_t)b * wStride;

    int srow = lane >> 2, schk = (lane & 3) * 8;
    const short* agp  = Ab  + (size_t)(m0 + w * 16 + srow) * K + schk;
    const short* wgp0 = Wtb + (size_t)(j0 + w * 32 + srow) * K + schk;
    const short* wgp1 = Wtb + (size_t)(j0 + w * 32 + 16 + srow) * K + schk;
    short* alp  = As + w * 512;            // w*16 rows * 32
    short* wlp0 = Ws + w * 1024;           // w*32 rows * 32
    short* wlp1 = Ws + w * 1024 + 512;

    f4 acc[2][4];
#pragma unroll
    for (int i = 0; i < 2; ++i)
#pragma unroll
        for (int j = 0; j < 4; ++j) acc[i][j] = zerof4();

    GLL16(agp,  alp);
    GLL16(wgp0, wlp0);
    GLL16(wgp1, wlp1);
    __syncthreads();

    int nk = K >> 5;
    for (int t = 0; t < nk; ++t) {
        int bb = t & 1, nb2 = bb ^ 1;
        if (t + 1 < nk) {
            int ko = (t + 1) << 5;
            GLL16(agp + ko,  alp + nb2 * 2048);
            GLL16(wgp0 + ko, wlp0 + nb2 * 4096);
            GLL16(wgp1 + ko, wlp1 + nb2 * 4096);
        }
        bf8 af[2], bfr[4];
#pragma unroll
        for (int fi = 0; fi < 2; ++fi)
            af[fi] = *(const bf8*)(As + bb * 2048 + (wr * 32 + fi * 16 + lr) * 32 + lg * 8);
#pragma unroll
        for (int fj = 0; fj < 4; ++fj)
            bfr[fj] = *(const bf8*)(Ws + bb * 4096 + (wc * 64 + fj * 16 + lr) * 32 + lg * 8);
#pragma unroll
        for (int fi = 0; fi < 2; ++fi)
#pragma unroll
            for (int fj = 0; fj < 4; ++fj)
                acc[fi][fj] = MFMA(af[fi], bfr[fj], acc[fi][fj]);
        __syncthreads();
    }

    if (EPI == 1 || EPI == 2) {
        float* out = (float*)outv + (size_t)b * oStride;
        const float* rp = res + (size_t)b * oStride;
#pragma unroll
        for (int fi = 0; fi < 2; ++fi) {
            int mbase = m0 + wr * 32 + fi * 16 + lg * 4;
            float4 bq = *(const float4*)(bias + mbase);
            float bvr[4] = {bq.x, bq.y, bq.z, bq.w};
            float sg = 0.f, ssg = 0.f;
#pragma unroll
            for (int reg = 0; reg < 4; ++reg) {
                size_t ro = (size_t)(mbase + reg) * J + j0 + wc * 64;
#pragma unroll
                for (int fj = 0; fj < 4; ++fj) {
                    size_t idx = ro + fj * 16 + lr;
                    float v = acc[fi][fj][reg] + bvr[reg] + rp[idx];
                    out[idx] = v;
                    if (EPI == 2) { sg += v; ssg += v * v; }
                }
            }
            if (EPI == 2) {
#pragma unroll
                for (int off = 32; off; off >>= 1) {
                    sg  += __shfl_down(sg,  off);
                    ssg += __shfl_down(ssg, off);
                }
                if (lane == 0) {
                    int g = mbase >> 4;
                    atomicAdd(&gstat[b * 64 + g * 2], sg);
                    atomicAdd(&gstat[b * 64 + g * 2 + 1], ssg);
                }
            }
        }
    } else if (EPI == 3) {
        if (j0 < 1024) {
            short* out = (short*)outv + (size_t)b * oStride;
#pragma unroll
            for (int fi = 0; fi < 2; ++fi)
#pragma unroll
                for (int reg = 0; reg < 4; ++reg) {
                    int m = m0 + wr * 32 + fi * 16 + lg * 4 + reg;
#pragma unroll
                    for (int fj = 0; fj < 4; ++fj)
                        out[(size_t)m * 1024 + j0 + wc * 64 + fj * 16 + lr] = sf(acc[fi][fj][reg]);
                }
        } else {
            short* Vgp = (short*)out2v + (size_t)b * o2Stride;
#pragma unroll
            for (int fi = 0; fi < 2; ++fi) {
                int n = m0 + wr * 32 + fi * 16 + lg * 4;
#pragma unroll
                for (int fj = 0; fj < 4; ++fj) {
                    int dg = j0 - 1024 + wc * 64 + fj * 16 + lr;
                    s4v v;
#pragma unroll
                    for (int reg = 0; reg < 4; ++reg) v[reg] = sf(acc[fi][fj][reg]);
                    *(s4v*)(Vgp + (size_t)dg * 1024 + n) = v;
                }
            }
        }
    } else {  // EPI == 4
        if (j0 < 512) {
            short* out = (short*)outv + (size_t)b * oStride;
#pragma unroll
            for (int fi = 0; fi < 2; ++fi)
#pragma unroll
                for (int reg = 0; reg < 4; ++reg) {
                    int m = m0 + wr * 32 + fi * 16 + lg * 4 + reg;
                    if (m < M) {
#pragma unroll
                        for (int fj = 0; fj < 4; ++fj)
                            out[(size_t)m * 512 + j0 + wc * 64 + fj * 16 + lr] = sf(acc[fi][fj][reg]);
                    }
                }
        } else {
            short* vt = (short*)out2v + (size_t)b * o2Stride;
#pragma unroll
            for (int fi = 0; fi < 2; ++fi) {
                int l0 = m0 + wr * 32 + fi * 16 + lg * 4;
                if (l0 < 80) {
#pragma unroll
                    for (int fj = 0; fj < 4; ++fj) {
                        int dg = j0 - 512 + wc * 64 + fj * 16 + lr;
                        s4v v;
#pragma unroll
                        for (int reg = 0; reg < 4; ++reg) v[reg] = sf(acc[fi][fj][reg]);
                        *(s4v*)(vt + (size_t)dg * 80 + l0) = v;
                    }
                }
            }
        }
    }
}

template<int EPI>
__global__ __launch_bounds__(256)
void gemm_std(const short* __restrict__ A, const short* __restrict__ Wt,
              const float* __restrict__ bias, const float* __restrict__ res,
              void* __restrict__ outv, void* __restrict__ out2v, float* __restrict__ gstat,
              int M, int K, int J, long aStride, long wStride, long oStride, long o2Stride)
{
    __shared__ short As[2 * 64 * 32];
    __shared__ short Ws[2 * 128 * 32];
    gemm_body<EPI>(As, Ws, blockIdx.x * 128, blockIdx.y * 64, blockIdx.z,
                   A, Wt, bias, res, outv, out2v, gstat, M, K, J,
                   aStride, wStride, oStride, o2Stride);
}

// merged qkv + kv launcher: grid (12, 18, 4). by<16 -> qkv; by>=16,bx<8 -> kv
__global__ __launch_bounds__(256)
void gemm_qkv_kv(const short* __restrict__ h1b, const short* __restrict__ qkvwT,
                 short* __restrict__ qkb, short* __restrict__ Vg,
                 const short* __restrict__ ctxb, const short* __restrict__ cakwT,
                 short* __restrict__ k2b, short* __restrict__ v2t)
{
    __shared__ short As[2 * 64 * 32];
    __shared__ short Ws[2 * 128 * 32];
    if (blockIdx.y < 16) {
        gemm_body<3>(As, Ws, blockIdx.x * 128, blockIdx.y * 64, blockIdx.z,
                     h1b, qkvwT, nullptr, nullptr, qkb, Vg, nullptr,
                     1024, 512, 1536, 524288L, 0L, 1048576L, 524288L);
    } else if (blockIdx.x < 8) {
        gemm_body<4>(As, Ws, blockIdx.x * 128, (blockIdx.y - 16) * 64, blockIdx.z,
                     ctxb, cakwT, nullptr, nullptr, k2b, v2t, nullptr,
                     77, 768, 1024, 59136L, 0L, 39424L, 40960L);
    }
}

// ---------------------------------------------------------------------------
// Fresnel attention v3 (unchanged).
// ---------------------------------------------------------------------------
__global__ __launch_bounds__(256)
void fresnel_attn_v3(const short* __restrict__ qkb, const short* __restrict__ Vg,
                     const short* __restrict__ tab, short* __restrict__ ao)
{
    int qb = blockIdx.x, h = blockIdx.y, b = blockIdx.z;
    int n0 = qb * 64;
    __shared__ short Ks[2][64][64];
    __shared__ short Vt[2][64][64];
    __shared__ short Ps[4][16][72];
    __shared__ short tabs[4032];
    int tid = threadIdx.x, w = tid >> 6, lane = tid & 63;
    int lr = lane & 15, lg = lane >> 4;
    const short* qp = qkb + (size_t)b * 1048576;
    const short* vp = Vg + ((size_t)b * 512 + h * 64) * 1024;

    for (int l = tid; l < 504; l += 256)
        *(bf8*)&tabs[l * 8] = *(const bf8*)(tab + l * 8);

    int q = n0 + w * 16 + lr;
    bf8 qf0 = *(const bf8*)(qp + (size_t)q * 1024 + h * 64 + lg * 8);
    bf8 qf1 = *(const bf8*)(qp + (size_t)q * 1024 + h * 64 + 32 + lg * 8);

    int sr0 = tid >> 3, sc0 = tid & 7;
    int sr1 = 32 + sr0;
    int sw0 = ((sc0 ^ (sr0 & 7))) * 8;
    int sw1 = ((sc0 ^ (sr1 & 7))) * 8;

    *(bf8*)&Ks[0][sr0][sw0] = *(const bf8*)(qp + (size_t)sr0 * 1024 + 512 + h * 64 + sc0 * 8);
    *(bf8*)&Ks[0][sr1][sw1] = *(const bf8*)(qp + (size_t)sr1 * 1024 + 512 + h * 64 + sc0 * 8);
    *(bf8*)&Vt[0][sr0][sw0] = *(const bf8*)(vp + (size_t)sr0 * 1024 + sc0 * 8);
    *(bf8*)&Vt[0][sr1][sw1] = *(const bf8*)(vp + (size_t)sr1 * 1024 + sc0 * 8);
    __syncthreads();

    float mrun = -1e30f, lrun = 0.f;
    f4 o[4];
#pragma unroll
    for (int i = 0; i < 4; ++i) o[i] = zerof4();

    int ybase = (q >> 5) + 31;
    int xbase = (q & 31) + 31 - lg * 4;
    int rsw = lr & 7;
    int rc0 = (lg ^ rsw) * 8;
    int rc1 = ((4 + lg) ^ rsw) * 8;

    for (int t = 0; t < 16; ++t) {
        int cur = t & 1;
        int m0 = t << 6;
        bool more = t < 15;
        bf8 nk0, nk1, nv0, nv1;
        if (more) {
            int m1 = m0 + 64;
            nk0 = *(const bf8*)(qp + (size_t)(m1 + sr0) * 1024 + 512 + h * 64 + sc0 * 8);
            nk1 = *(const bf8*)(qp + (size_t)(m1 + sr1) * 1024 + 512 + h * 64 + sc0 * 8);
            nv0 = *(const bf8*)(vp + (size_t)sr0 * 1024 + m1 + sc0 * 8);
            nv1 = *(const bf8*)(vp + (size_t)sr1 * 1024 + m1 + sc0 * 8);
        }

        f4 sa[4];
#pragma unroll
        for (int fj = 0; fj < 4; ++fj) sa[fj] = zerof4();
        __builtin_amdgcn_s_setprio(1);
#pragma unroll
        for (int fj = 0; fj < 4; ++fj)
            sa[fj] = MFMA(*(const bf8*)&Ks[cur][fj * 16 + lr][rc0], qf0, sa[fj]);
#pragma unroll
        for (int fj = 0; fj < 4; ++fj)
            sa[fj] = MFMA(*(const bf8*)&Ks[cur][fj * 16 + lr][rc1], qf1, sa[fj]);
        __builtin_amdgcn_s_setprio(0);

        int yb = ybase - (m0 >> 5);
        float pv[4][4];
        float tmax = -1e30f;
#pragma unroll
        for (int fj = 0; fj < 4; ++fj) {
            int rowoff = (yb - (fj >> 1)) * 63 + xbase - (fj & 1) * 16;
#pragma unroll
            for (int reg = 0; reg < 4; ++reg) {
                float t2 = fmaf(sa[fj][reg], 0.18033688011112042f, fs(tabs[rowoff - reg]));
                pv[fj][reg] = t2;
                tmax = fmaxf(tmax, t2);
            }
        }
        if (__any(tmax > mrun + 8.f)) {
            tmax = fmaxf(tmax, __shfl_xor(tmax, 16));
            tmax = fmaxf(tmax, __shfl_xor(tmax, 32));
            float mnew = fmaxf(mrun, tmax);
            float rsc = EXP2(mrun - mnew);
            mrun = mnew;
            lrun *= rsc;
#pragma unroll
            for (int fd = 0; fd < 4; ++fd)
#pragma unroll
                for (int reg = 0; reg < 4; ++reg) o[fd][reg] *= rsc;
        }
        float psum = 0.f;
#pragma unroll
        for (int fj = 0; fj < 4; ++fj) {
            float p0 = EXP2(pv[fj][0] - mrun);
            float p1 = EXP2(pv[fj][1] - mrun);
            float p2 = EXP2(pv[fj][2] - mrun);
            float p3 = EXP2(pv[fj][3] - mrun);
            psum += (p0 + p1) + (p2 + p3);
            int r01, r23;
            asm("v_cvt_pk_bf16_f32 %0, %1, %2" : "=v"(r01) : "v"(p0), "v"(p1));
            asm("v_cvt_pk_bf16_f32 %0, %1, %2" : "=v"(r23) : "v"(p2), "v"(p3));
            int2 pr; pr.x = r01; pr.y = r23;
            *(int2*)&Ps[w][lr][fj * 16 + lg * 4] = pr;
        }
        psum += __shfl_xor(psum, 16);
        psum += __shfl_xor(psum, 32);
        lrun += psum;

        bf8 pa0 = *(const bf8*)&Ps[w][lr][lg * 8];
        bf8 pa1 = *(const bf8*)&Ps[w][lr][32 + lg * 8];
        __builtin_amdgcn_s_setprio(1);
#pragma unroll
        for (int fd = 0; fd < 4; ++fd) {
            o[fd] = MFMA(*(const bf8*)&Vt[cur][fd * 16 + lr][rc0], pa0, o[fd]);
            o[fd] = MFMA(*(const bf8*)&Vt[cur][fd * 16 + lr][rc1], pa1, o[fd]);
        }
        __builtin_amdgcn_s_setprio(0);

        if (more) {
            int nb = cur ^ 1;
            *(bf8*)&Ks[nb][sr0][sw0] = nk0;
            *(bf8*)&Ks[nb][sr1][sw1] = nk1;
            *(bf8*)&Vt[nb][sr0][sw0] = nv0;
            *(bf8*)&Vt[nb][sr1][sw1] = nv1;
        }
        __syncthreads();
    }

    float inv = 1.f / lrun;
    size_t rb = ((size_t)b * N_ + q) * 512 + h * 64;
#pragma unroll
    for (int fd = 0; fd < 4; ++fd) {
        s4v ov;
#pragma unroll
        for (int reg = 0; reg < 4; ++reg) ov[reg] = sf(o[fd][reg] * inv);
        *(s4v*)(ao + rb + fd * 16 + lg * 4) = ov;
    }
}

// ---------------------------------------------------------------------------
// Cross attention with fused GroupNorm2 + q-projection.
// x1: [b][512][1024] fp32 (pre-norm); gstat: group sums; gn2w/gn2b per-ch.
// q-tile = gn2(x1)[n0:n0+64] @ qwT[h*64:+64]^T via 16-step mini-GEMM, where
// the hq staging reads x1 [c][n] (coalesced), normalizes, transposes to LDS.
// wq staged via global_load_lds (linear [64][32]).
// ---------------------------------------------------------------------------
__global__ __launch_bounds__(256)
void cross_attn_fused(const float* __restrict__ x1, const float* __restrict__ gstat,
                      const float* __restrict__ gn2w, const float* __restrict__ gn2b,
                      const short* __restrict__ qwT,
                      const short* __restrict__ k2, const short* __restrict__ v2t,
                      short* __restrict__ ao2)
{
    int qb = blockIdx.x, h = blockIdx.y, b = blockIdx.z;
    int n0 = qb * 64;
    __shared__ short hq[2][64][40];
    __shared__ short wq[2 * 64 * 32];
    __shared__ short Qs[64][72], Ks[96][72], Vt[64][104];
    __shared__ short Ps[4][16][104];
    __shared__ float smu[32], srs[32];
    int tid = threadIdx.x, w = tid >> 6, lane = tid & 63;
    int lr = lane & 15, lg = lane >> 4;

    // group stats for gn2
    if (tid < 32) {
        float S  = gstat[b * 64 + tid * 2];
        float SS = gstat[b * 64 + tid * 2 + 1];
        float mu = S * (1.f / 16384.f);
        float var = SS * (1.f / 16384.f) - mu * mu;
        smu[tid] = mu;
        srs[tid] = rsqrtf(var + 1e-5f);
    }

    // stage K and V
    for (int l = tid; l < 768; l += 256) {
        int m = l >> 3, dq = l & 7;
        bf8 v = zero8();
        if (m < L_) v = *(const bf8*)(k2 + ((size_t)b * L_ + m) * 512 + h * 64 + dq * 8);
        *(bf8*)&Ks[m][dq * 8] = v;
    }
    for (int l = tid; l < 768; l += 256) {
        int d = l / 12, cq = l % 12;
        bf8 v = zero8();
        if (cq < 10) v = *(const bf8*)(v2t + ((size_t)b * 512 + h * 64 + d) * 80 + cq * 8);
        *(bf8*)&Vt[d][cq * 8] = v;
    }

    // wq global_load_lds setup
    int srow = lane >> 2, schk = (lane & 3) * 8;
    const short* wgp = qwT + (size_t)(h * 64 + w * 16 + srow) * 512 + schk;
    short* wlp = wq + w * 512;

    // hq staging setup: thread covers c rows {cr, cr+16} of the 32-col step,
    // n cols [cn, cn+4)
    int cr = tid >> 4, cn = (tid & 15) * 4;
    const float* xp0 = x1 + ((size_t)b * 512 + cr) * 1024 + n0 + cn;
    const float* xp1 = xp0 + 16 * 1024;

    // prologue: issue wq step0, load x1 step0
    GLL16(wgp, wlp);
    float4 f0 = *(const float4*)(xp0);
    float4 f1 = *(const float4*)(xp1);
    float wv0 = gn2w[cr],      bv0 = gn2b[cr];
    float wv1 = gn2w[cr + 16], bv1 = gn2b[cr + 16];
    __syncthreads();                       // smu/srs visible; wq0 drained
    {
        float mu0 = smu[0], rs0 = srs[0];  // step0: groups 0 and 1
        float mu1 = smu[1], rs1 = srs[1];
        float a0 = rs0 * wv0, a1 = rs1 * wv1;
        float c0 = bv0 - mu0 * a0, c1 = bv1 - mu1 * a1;
#pragma unroll
        for (int i = 0; i < 4; ++i) {
            hq[0][cn + i][cr]      = sf(f0[i] * a0 + c0);
            hq[0][cn + i][cr + 16] = sf(f1[i] * a1 + c1);
        }
    }
    __syncthreads();                       // hq0 ready

    f4 qacc[4];
#pragma unroll
    for (int j = 0; j < 4; ++j) qacc[j] = zerof4();
    for (int t = 0; t < 16; ++t) {
        int cur = t & 1, nb = cur ^ 1;
        bool more = t < 15;
        float4 nf0, nf1;
        float nw0, nb0, nw1, nb1;
        if (more) {
            int ko = (t + 1) << 5;
            GLL16(wgp + ko, wlp + nb * 2048);
            nf0 = *(const float4*)(xp0 + ko * 1024);
            nf1 = *(const float4*)(xp1 + ko * 1024);
            nw0 = gn2w[ko + cr];      nb0 = gn2b[ko + cr];
            nw1 = gn2w[ko + cr + 16]; nb1 = gn2b[ko + cr + 16];
        }
        bf8 af = *(const bf8*)&hq[cur][w * 16 + lr][lg * 8];
#pragma unroll
        for (int fj = 0; fj < 4; ++fj)
            qacc[fj] = MFMA(af, *(const bf8*)(wq + cur * 2048 + (fj * 16 + lr) * 32 + lg * 8), qacc[fj]);
        if (more) {
            int g0 = (t + 1) * 2, g1 = g0 + 1;
            float mu0 = smu[g0], rs0 = srs[g0];
            float mu1 = smu[g1], rs1 = srs[g1];
            float a0 = rs0 * nw0, a1 = rs1 * nw1;
            float c0 = nb0 - mu0 * a0, c1 = nb1 - mu1 * a1;
#pragma unroll
            for (int i = 0; i < 4; ++i) {
                hq[nb][cn + i][cr]      = sf(nf0[i] * a0 + c0);
                hq[nb][cn + i][cr + 16] = sf(nf1[i] * a1 + c1);
            }
        }
        __syncthreads();
    }
    // write q-tile to Qs: n = w*16+lg*4+reg, d = fj*16+lr
#pragma unroll
    for (int fj = 0; fj < 4; ++fj)
#pragma unroll
        for (int reg = 0; reg < 4; ++reg)
            Qs[w * 16 + lg * 4 + reg][fj * 16 + lr] = sf(qacc[fj][reg]);
    __syncthreads();

    f4 sacc[6];
#pragma unroll
    for (int fj = 0; fj < 6; ++fj) sacc[fj] = zerof4();
    __builtin_amdgcn_s_setprio(1);
#pragma unroll
    for (int kc = 0; kc < 2; ++kc) {
        bf8 aq = *(const bf8*)&Qs[w * 16 + lr][kc * 32 + lg * 8];
#pragma unroll
        for (int fj = 0; fj < 6; ++fj)
            sacc[fj] = MFMA(aq, *(const bf8*)&Ks[fj * 16 + lr][kc * 32 + lg * 8], sacc[fj]);
    }
    __builtin_amdgcn_s_setprio(0);

    float rinv[4];
#pragma unroll
    for (int reg = 0; reg < 4; ++reg) {
        float sv[6];
#pragma unroll
        for (int fj = 0; fj < 6; ++fj) {
            int m = fj * 16 + lr;
            sv[fj] = (m < L_) ? sacc[fj][reg] * 0.125f : -30000.f;
        }
        float mx = sv[0];
#pragma unroll
        for (int fj = 1; fj < 6; ++fj) mx = fmaxf(mx, sv[fj]);
#pragma unroll
        for (int off = 1; off < 16; off <<= 1) mx = fmaxf(mx, __shfl_xor(mx, off));
        float psum = 0.f;
#pragma unroll
        for (int fj = 0; fj < 6; ++fj) {
            float p = __expf(sv[fj] - mx);
            psum += p;
            Ps[w][lg * 4 + reg][fj * 16 + lr] = sf(p);
        }
#pragma unroll
        for (int off = 1; off < 16; off <<= 1) psum += __shfl_xor(psum, off);
        rinv[reg] = 1.f / psum;
    }
    __syncthreads();

    f4 o[4];
#pragma unroll
    for (int fd = 0; fd < 4; ++fd) o[fd] = zerof4();
    __builtin_amdgcn_s_setprio(1);
#pragma unroll
    for (int kc = 0; kc < 3; ++kc) {
        bf8 ap = *(const bf8*)&Ps[w][lr][kc * 32 + lg * 8];
#pragma unroll
        for (int fd = 0; fd < 4; ++fd)
            o[fd] = MFMA(ap, *(const bf8*)&Vt[fd * 16 + lr][kc * 32 + lg * 8], o[fd]);
    }
    __builtin_amdgcn_s_setprio(0);

#pragma unroll
    for (int reg = 0; reg < 4; ++reg) {
        size_t rb = ((size_t)b * N_ + n0 + w * 16 + lg * 4 + reg) * 512 + h * 64;
#pragma unroll
        for (int fd = 0; fd < 4; ++fd)
            ao2[rb + fd * 16 + lr] = sf(o[fd][reg] * rinv[reg]);
    }
}

// ---------------------------------------------------------------------------
extern "C" void kernel_launch(void* const* d_in, const int* in_sizes, int n_in,
                              void* d_out, int out_size, void* d_ws, size_t ws_size,
                              hipStream_t stream)
{
    const float* x    = (const float*)d_in[0];
    const float* ctx  = (const float*)d_in[1];
    const float* gn1w = (const float*)d_in[2];
    const float* gn1b = (const float*)d_in[3];
    const float* gn2w = (const float*)d_in[4];
    const float* gn2b = (const float*)d_in[5];
    const float* qkvw = (const float*)d_in[6];
    const float* faow = (const float*)d_in[7];
    const float* faob = (const float*)d_in[8];
    const float* wl   = (const float*)d_in[9];
    const float* caqw = (const float*)d_in[10];
    const float* cakw = (const float*)d_in[11];
    const float* cavw = (const float*)d_in[12];
    const float* caow = (const float*)d_in[13];
    const float* caob = (const float*)d_in[14];
    float* out = (float*)d_out;
    char* ws = (char*)d_ws;

    float* x1    = (float*)(ws + 0);            // 8 MB fp32 [b][c][n]
    short* qkb   = (short*)(ws + 8388608);      // 8 MB bf16 [b][n][1024] (q|k)
    short* Vg    = (short*)(ws + 16777216);     // 4 MB bf16 [b][512][1024]
    short* h1b   = (short*)(ws + 20971520);     // 4 MB [b][n][512] (h1)
    short* ao    = (short*)(ws + 25165824);     // 4 MB [b][n][512] (ao / ao2)
    float* gstat = (float*)(ws + 29360128);     // 1 KB (4 b x 32 g x 2)
    short* qkvwT = (short*)(ws + 33554432);     // 1.5 MB  [1536][512]
    short* faowT = (short*)(ws + 35127296);     // 0.5 MB  [512][512]
    short* caqwT = (short*)(ws + 35651584);     // 0.5 MB
    short* cakwT = (short*)(ws + 36175872);     // 0.75 MB [512][768]
    short* cavwT = (short*)(ws + 36962304);     // 0.75 MB (contiguous after cakwT)
    short* caowT = (short*)(ws + 37748736);     // 0.5 MB
    short* k2b   = (short*)(ws + 38273024);     // 308 KB [b][77][512]
    short* v2t   = (short*)(ws + 38588416);     // 320 KB [b][512][80]
    short* ctxb  = (short*)(ws + 38916096);     // 462 KB
    short* tab   = (short*)(ws + 39389184);     // 8 KB

    // L1: gn1 + tab + gstat zero + weight transposes + ctx convert
    prep_mega<<<2679, 256, 0, stream>>>(x, gn1w, gn1b, h1b,
                                        wl, tab, gstat, qkvw, qkvwT, faow, faowT,
                                        caqw, caqwT, cakw, cakwT, cavw, cavwT,
                                        caow, caowT, ctx, ctxb);
    // L2: qkv (q|k -> qkb, v -> Vg transposed) + kv (k -> k2b, v -> v2t)
    gemm_qkv_kv<<<dim3(12, 18, 4), 256, 0, stream>>>(
        h1b, qkvwT, qkb, Vg, ctxb, cakwT, k2b, v2t);
    // L3
    fresnel_attn_v3<<<dim3(16, 8, 4), 256, 0, stream>>>(qkb, Vg, tab, ao);
    // L4: x1[c][n] = x + (ao @ fa_out_w)^T + b  (+ group-stat atomics)
    gemm_std<2><<<dim3(8, 8, 4), 256, 0, stream>>>(
        faowT, ao, faob, x, x1, nullptr, gstat, 512, 512, 1024,
        0L, 524288L, 524288L, 0L);
    // L5: cross attention with fused gn2 + q-projection
    cross_attn_fused<<<dim3(16, 8, 4), 256, 0, stream>>>(
        x1, gstat, gn2w, gn2b, caqwT, k2b, v2t, ao);
    // L6: out[c][n] = x1 + (ao2 @ ca_out_w)^T + b
    gemm_std<1><<<dim3(8, 8, 4), 256, 0, stream>>>(
        caowT, ao, caob, x1, out, nullptr, nullptr, 512, 512, 1024,
        0L, 524288L, 524288L, 0L);
}